// Round 1
// baseline (800.660 us; speedup 1.0000x reference)
//
#include <hip/hip_runtime.h>
#include <hip/hip_bf16.h>
#include <hip/hip_fp16.h>

// Problem dims (hard-coded): B=8, S=4096, DIM=1024, M=1024
#define ROWS_TOT 32768
#define KDIM 1024

typedef __attribute__((ext_vector_type(8))) __bf16    bf16x8;
typedef __attribute__((ext_vector_type(4))) __bf16    bf16x4;
typedef __attribute__((ext_vector_type(8))) _Float16  half8;
typedef __attribute__((ext_vector_type(4))) _Float16  half4v;
typedef __attribute__((ext_vector_type(4))) float     f32x4;

// async global->LDS, 16B per lane. LDS base must be wave-uniform; HW adds lane*16.
__device__ __forceinline__ void g2l16(const void* g, void* l) {
  __builtin_amdgcn_global_load_lds(
      (const __attribute__((address_space(1))) unsigned int*)g,
      (__attribute__((address_space(3))) unsigned int*)l, 16, 0, 0);
}

__device__ __forceinline__ void split2(float v, __bf16& h, __bf16& l) {
  h = (__bf16)v;
  l = (__bf16)(v - (float)h);
}

// ---------------------------------------------------------------------------
// prep: elementwise split W and mem into bf16 hi/lo (layouts already B^T-friendly)
__global__ __launch_bounds__(256) void prep_wm(
    const float* __restrict__ W, const float* __restrict__ mem,
    __bf16* __restrict__ Wh, __bf16* __restrict__ Wl,
    __bf16* __restrict__ Mh, __bf16* __restrict__ Ml) {
  int i = blockIdx.x * 256 + threadIdx.x;   // 1M threads exactly
  float w = W[i];
  __bf16 h, l;
  split2(w, h, l); Wh[i] = h; Wl[i] = l;
  float m = mem[i];
  split2(m, h, l); Mh[i] = h; Ml[i] = l;
}

// transpose mem [m][d] -> memT fp16 [d][m] (B^T layout for GEMM3)
__global__ __launch_bounds__(256) void transpose_mem(
    const float* __restrict__ mem, _Float16* __restrict__ memT) {
  __shared__ float tl[32][33];
  int bx = blockIdx.x, by = blockIdx.y;
  int tx = threadIdx.x, ty = threadIdx.y;   // (32, 8)
#pragma unroll
  for (int j = 0; j < 4; ++j)
    tl[ty + 8 * j][tx] = mem[(by * 32 + ty + 8 * j) * 1024 + bx * 32 + tx];
  __syncthreads();
#pragma unroll
  for (int j = 0; j < 4; ++j)
    memT[(bx * 32 + ty + 8 * j) * 1024 + by * 32 + tx] =
        (_Float16)tl[tx][ty + 8 * j];
}

// ---------------------------------------------------------------------------
// Split-bf16 compensated GEMM, C = A @ B^T (3 MFMA products: hh + hl + lh).
// MODE 0: A = x (fp32, split inline during staging); epilogue adds bias and
//         writes q as bf16 hi/lo pair.
// MODE 1: A = pre-split q_hi/q_lo; epilogue writes fp32 attn.
// 128x128 tile, BK=32, 256 threads (4 waves, 2x2 wave grid of 64x64).
template <int MODE>
__global__ __launch_bounds__(256) void gemm12_kernel(
    const float* __restrict__ X,
    const __bf16* __restrict__ Agh, const __bf16* __restrict__ Agl,
    const __bf16* __restrict__ Bgh, const __bf16* __restrict__ Bgl,
    const float* __restrict__ bias,
    __bf16* __restrict__ Oh, __bf16* __restrict__ Ol,
    float* __restrict__ Of) {
  __shared__ __attribute__((aligned(16))) __bf16 Ah[128 * 32];
  __shared__ __attribute__((aligned(16))) __bf16 Al[128 * 32];
  __shared__ __attribute__((aligned(16))) __bf16 Bh[128 * 32];
  __shared__ __attribute__((aligned(16))) __bf16 Bl[128 * 32];

  const int t = threadIdx.x;
  const int wave = t >> 6;
  const int lane = t & 63;
  const int wm = wave & 1, wn = wave >> 1;
  const int tileM = blockIdx.y * 128;
  const int tileN = blockIdx.x * 128;

  f32x4 acc[4][4] = {};

  const int rS = lane >> 2;        // row within 16-row staging group
  const int cS = (lane & 3) * 8;   // k element offset within BK=32

  for (int kt = 0; kt < KDIM / 32; ++kt) {
    const int k0 = kt * 32;
    __syncthreads();
    // --- stage B^T tile (rows tileN..tileN+127, k0..k0+31), hi+lo
#pragma unroll
    for (int i = 0; i < 2; ++i) {
      const int rb = i * 64 + wave * 16;  // wave-uniform LDS row base
      const int gro = (tileN + rb + rS) * KDIM + k0 + cS;
      g2l16(Bgh + gro, &Bh[rb * 32]);
      g2l16(Bgl + gro, &Bl[rb * 32]);
    }
    if constexpr (MODE == 1) {
#pragma unroll
      for (int i = 0; i < 2; ++i) {
        const int rb = i * 64 + wave * 16;
        const int gro = (tileM + rb + rS) * KDIM + k0 + cS;
        g2l16(Agh + gro, &Ah[rb * 32]);
        g2l16(Agl + gro, &Al[rb * 32]);
      }
    } else {
      // inline fp32 -> bf16 hi/lo split of x during staging
#pragma unroll
      for (int i = 0; i < 4; ++i) {
        const int idx = i * 256 + t;
        const int row = idx >> 3;
        const int c4 = (idx & 7) * 4;
        const float4 v = *(const float4*)(X + (tileM + row) * KDIM + k0 + c4);
        float vv[4] = {v.x, v.y, v.z, v.w};
        bf16x4 h, l;
#pragma unroll
        for (int j = 0; j < 4; ++j) {
          __bf16 hh = (__bf16)vv[j];
          h[j] = hh;
          l[j] = (__bf16)(vv[j] - (float)hh);
        }
        *(bf16x4*)(&Ah[row * 32 + c4]) = h;
        *(bf16x4*)(&Al[row * 32 + c4]) = l;
      }
    }
    __syncthreads();

    const int fr = lane & 15;
    const int fk = (lane >> 4) * 8;
    bf16x8 afh[4], afl[4], bfh[4], bfl[4];
#pragma unroll
    for (int mf = 0; mf < 4; ++mf) {
      const int r = wm * 64 + mf * 16 + fr;
      afh[mf] = *(const bf16x8*)(&Ah[r * 32 + fk]);
      afl[mf] = *(const bf16x8*)(&Al[r * 32 + fk]);
    }
#pragma unroll
    for (int nf = 0; nf < 4; ++nf) {
      const int r = wn * 64 + nf * 16 + fr;
      bfh[nf] = *(const bf16x8*)(&Bh[r * 32 + fk]);
      bfl[nf] = *(const bf16x8*)(&Bl[r * 32 + fk]);
    }
#pragma unroll
    for (int mf = 0; mf < 4; ++mf)
#pragma unroll
      for (int nf = 0; nf < 4; ++nf) {
        acc[mf][nf] = __builtin_amdgcn_mfma_f32_16x16x32_bf16(afh[mf], bfh[nf], acc[mf][nf], 0, 0, 0);
        acc[mf][nf] = __builtin_amdgcn_mfma_f32_16x16x32_bf16(afh[mf], bfl[nf], acc[mf][nf], 0, 0, 0);
        acc[mf][nf] = __builtin_amdgcn_mfma_f32_16x16x32_bf16(afl[mf], bfh[nf], acc[mf][nf], 0, 0, 0);
      }
  }

  // --- epilogue. C/D layout: col = lane&15, row = (lane>>4)*4 + reg
  const int er = (lane >> 4) * 4;
  const int ec = lane & 15;
#pragma unroll
  for (int nf = 0; nf < 4; ++nf) {
    const int col = tileN + wn * 64 + nf * 16 + ec;
    float bv = 0.0f;
    if constexpr (MODE == 0) bv = bias[col];
#pragma unroll
    for (int mf = 0; mf < 4; ++mf) {
#pragma unroll
      for (int r = 0; r < 4; ++r) {
        const int row = tileM + wm * 64 + mf * 16 + er + r;
        float v = acc[mf][nf][r];
        if constexpr (MODE == 0) {
          v += bv;
          __bf16 h = (__bf16)v;
          Oh[row * KDIM + col] = h;
          Ol[row * KDIM + col] = (__bf16)(v - (float)h);
        } else {
          Of[row * KDIM + col] = v;
        }
      }
    }
  }
}

// ---------------------------------------------------------------------------
// softmax over M=1024 per row; attn fp32 in, probs fp16 out. 1 row / block.
__global__ __launch_bounds__(256) void softmax_k(
    const float* __restrict__ attn, _Float16* __restrict__ probs) {
  const int row = blockIdx.x;
  const int t = threadIdx.x;
  const int wave = t >> 6, lane = t & 63;
  __shared__ float redm[4];
  __shared__ float reds[4];

  float4 v = ((const float4*)(attn + (size_t)row * 1024))[t];
  float m = fmaxf(fmaxf(v.x, v.y), fmaxf(v.z, v.w));
#pragma unroll
  for (int off = 32; off; off >>= 1) m = fmaxf(m, __shfl_xor(m, off));
  if (lane == 0) redm[wave] = m;
  __syncthreads();
  m = fmaxf(fmaxf(redm[0], redm[1]), fmaxf(redm[2], redm[3]));

  float e0 = expf(v.x - m), e1 = expf(v.y - m);
  float e2 = expf(v.z - m), e3 = expf(v.w - m);
  float s = e0 + e1 + e2 + e3;
#pragma unroll
  for (int off = 32; off; off >>= 1) s += __shfl_xor(s, off);
  if (lane == 0) reds[wave] = s;
  __syncthreads();
  s = reds[0] + reds[1] + reds[2] + reds[3];
  const float inv = 1.0f / s;

  half4v o;
  o[0] = (_Float16)(e0 * inv);
  o[1] = (_Float16)(e1 * inv);
  o[2] = (_Float16)(e2 * inv);
  o[3] = (_Float16)(e3 * inv);
  ((half4v*)(probs + (size_t)row * 1024))[t] = o;
}

// ---------------------------------------------------------------------------
// GEMM3: context = probs @ memT^T, fp16 single-product MFMA, fp32 out.
__global__ __launch_bounds__(256) void gemm3_kernel(
    const _Float16* __restrict__ Ag, const _Float16* __restrict__ Bg,
    float* __restrict__ Of) {
  __shared__ __attribute__((aligned(16))) _Float16 As[128 * 32];
  __shared__ __attribute__((aligned(16))) _Float16 Bs[128 * 32];

  const int t = threadIdx.x;
  const int wave = t >> 6;
  const int lane = t & 63;
  const int wm = wave & 1, wn = wave >> 1;
  const int tileM = blockIdx.y * 128;
  const int tileN = blockIdx.x * 128;

  f32x4 acc[4][4] = {};
  const int rS = lane >> 2;
  const int cS = (lane & 3) * 8;

  for (int kt = 0; kt < KDIM / 32; ++kt) {
    const int k0 = kt * 32;
    __syncthreads();
#pragma unroll
    for (int i = 0; i < 2; ++i) {
      const int rb = i * 64 + wave * 16;
      g2l16(Ag + (tileM + rb + rS) * KDIM + k0 + cS, &As[rb * 32]);
      g2l16(Bg + (tileN + rb + rS) * KDIM + k0 + cS, &Bs[rb * 32]);
    }
    __syncthreads();

    const int fr = lane & 15;
    const int fk = (lane >> 4) * 8;
    half8 af[4], bf[4];
#pragma unroll
    for (int mf = 0; mf < 4; ++mf)
      af[mf] = *(const half8*)(&As[(wm * 64 + mf * 16 + fr) * 32 + fk]);
#pragma unroll
    for (int nf = 0; nf < 4; ++nf)
      bf[nf] = *(const half8*)(&Bs[(wn * 64 + nf * 16 + fr) * 32 + fk]);
#pragma unroll
    for (int mf = 0; mf < 4; ++mf)
#pragma unroll
      for (int nf = 0; nf < 4; ++nf)
        acc[mf][nf] = __builtin_amdgcn_mfma_f32_16x16x32_f16(af[mf], bf[nf], acc[mf][nf], 0, 0, 0);
  }

  const int er = (lane >> 4) * 4;
  const int ec = lane & 15;
#pragma unroll
  for (int nf = 0; nf < 4; ++nf) {
    const int col = tileN + wn * 64 + nf * 16 + ec;
#pragma unroll
    for (int mf = 0; mf < 4; ++mf)
#pragma unroll
      for (int r = 0; r < 4; ++r) {
        const int row = tileM + wm * 64 + mf * 16 + er + r;
        Of[row * KDIM + col] = acc[mf][nf][r];
      }
  }
}

// ---------------------------------------------------------------------------
extern "C" void kernel_launch(void* const* d_in, const int* in_sizes, int n_in,
                              void* d_out, int out_size, void* d_ws, size_t ws_size,
                              hipStream_t stream) {
  const float* x   = (const float*)d_in[0];   // [32768][1024]
  const float* W   = (const float*)d_in[1];   // [1024][1024]  (out, in) = B^T layout
  const float* b   = (const float*)d_in[2];   // [1024]
  const float* mem = (const float*)d_in[3];   // [1024][1024]  (m, e)    = B^T layout
  float* out = (float*)d_out;

  char* ws = (char*)d_ws;
  const size_t MB = 1024 * 1024;
  __bf16* q_hi   = (__bf16*)(ws);              // 64 MB
  __bf16* q_lo   = (__bf16*)(ws + 64 * MB);    // 64 MB
  float*  attn   = (float*)(ws + 128 * MB);    // 128 MB
  __bf16* Wh     = (__bf16*)(ws + 256 * MB);   // 2 MB
  __bf16* Wl     = (__bf16*)(ws + 258 * MB);   // 2 MB
  __bf16* Mh     = (__bf16*)(ws + 260 * MB);   // 2 MB
  __bf16* Ml     = (__bf16*)(ws + 262 * MB);   // 2 MB
  _Float16* memT = (_Float16*)(ws + 264 * MB); // 2 MB
  _Float16* probs = (_Float16*)(ws);           // overlays q_hi (dead after gemm2)

  prep_wm<<<4096, 256, 0, stream>>>(W, mem, Wh, Wl, Mh, Ml);
  transpose_mem<<<dim3(32, 32), dim3(32, 8), 0, stream>>>(mem, memT);

  // q = x @ W^T + b   (split-bf16, fp32-accurate; q stored as hi/lo bf16)
  gemm12_kernel<0><<<dim3(8, 256), 256, 0, stream>>>(
      x, nullptr, nullptr, Wh, Wl, b, q_hi, q_lo, nullptr);

  // attn = q @ mem^T  (split-bf16, fp32 logits)
  gemm12_kernel<1><<<dim3(8, 256), 256, 0, stream>>>(
      nullptr, q_hi, q_lo, Mh, Ml, nullptr, nullptr, nullptr, attn);

  softmax_k<<<32768, 256, 0, stream>>>(attn, probs);

  // context = probs @ mem  (fp16 single product via memT)
  gemm3_kernel<<<dim3(8, 256), 256, 0, stream>>>(probs, memT, out);
}